// Round 17
// baseline (153.950 us; speedup 1.0000x reference)
//
#include <hip/hip_runtime.h>

typedef short bf16x8 __attribute__((ext_vector_type(8)));
typedef float f32x2 __attribute__((ext_vector_type(2)));
typedef float f32x4 __attribute__((ext_vector_type(4)));
typedef float f32x16 __attribute__((ext_vector_type(16)));
typedef unsigned short ushort_t;
typedef unsigned short us8 __attribute__((ext_vector_type(8)));
typedef unsigned short us4 __attribute__((ext_vector_type(4)));
typedef unsigned int u32x4 __attribute__((ext_vector_type(4)));
typedef unsigned int uint2v __attribute__((ext_vector_type(2)));

#define MFMA16(a, b, c) __builtin_amdgcn_mfma_f32_16x16x32_bf16((a), (b), (c), 0, 0, 0)
#define MFMA32(a, b, c) __builtin_amdgcn_mfma_f32_32x32x16_bf16((a), (b), (c), 0, 0, 0)

template <int N> struct ic { static constexpr int value = N; };

static __device__ __forceinline__ ushort_t f2bf(float f) {
    unsigned int u = __builtin_bit_cast(unsigned int, f);
    u += 0x7FFFu + ((u >> 16) & 1u);   // RNE
    return (ushort_t)(u >> 16);
}

static __device__ __forceinline__ unsigned cvtpk(float lo, float hi) {
    unsigned r;
    asm("v_cvt_pk_bf16_f32 %0, %1, %2" : "=v"(r) : "v"(lo), "v"(hi));
    return r;
}

// global -> LDS direct async copy, 16B per lane (LDS dest = wave-uniform base + lane*16)
static __device__ __forceinline__ void gload16(const void* g, void* l) {
    __builtin_amdgcn_global_load_lds(
        (const __attribute__((address_space(1))) unsigned int*)g,
        (__attribute__((address_space(3))) unsigned int*)l,
        16, 0, 0);
}

// ---------------------------------------------------------------------------
// Convert 4 fp32 512x512 weight matrices to bf16 in CHUNK ORDER (r15-proven).
// ---------------------------------------------------------------------------
__global__ __launch_bounds__(256) void cvt_w(const float* __restrict__ W0,
                                             const float* __restrict__ W1,
                                             const float* __restrict__ W2,
                                             const float* __restrict__ W3,
                                             ushort_t* __restrict__ dst) {
    const float* src = (blockIdx.y == 0) ? W0 : (blockIdx.y == 1) ? W1
                     : (blockIdx.y == 2) ? W2 : W3;
    const int i = (blockIdx.x * 256 + threadIdx.x) * 8;
    const int n = i >> 9, k = i & 511;
    float4 f0 = *(const float4*)(src + i);
    float4 f1 = *(const float4*)(src + i + 4);
    unsigned tw[4] = {cvtpk(f0.x, f0.y), cvtpk(f0.z, f0.w),
                      cvtpk(f1.x, f1.y), cvtpk(f1.z, f1.w)};
    const int bn = n >> 6, r = n & 63;
    const int wn = r >> 5, j = (r >> 4) & 1, l15 = r & 15;
    const int kt = k >> 6, c = k & 63;
    const int kk = c >> 5, l16 = (c >> 3) & 3;
    const size_t off = (size_t)blockIdx.y * 262144 +
        (size_t)((bn * 8 + kt) * 4096 + (wn * 4 + j * 2 + kk) * 512 +
                 (l16 * 16 + l15) * 8);
    *(u32x4*)(dst + off) = *(u32x4*)tw;
}

// ---------------------------------------------------------------------------
// Fused Q/K/V projection NT-GEMM, 128x64 tile, BK=64, grid (512, 3).
// 16 MFMA/wave/iter (2x the 64x64 tile) with the same 2-barrier loop.
// A fp32 reg-staged + cvt_pk -> padded LDS; B chunk-ordered via gload_lds dbuf.
// Epilogue formulas (absolute m,n) identical to r15-verified.
// ---------------------------------------------------------------------------
__global__ __launch_bounds__(256) void gemm_qkv(const float* __restrict__ qi,
                                                const float* __restrict__ ki,
                                                const float* __restrict__ vi,
                                                const ushort_t* __restrict__ Wball,
                                                const float* __restrict__ bq,
                                                const float* __restrict__ bk,
                                                const float* __restrict__ bv,
                                                ushort_t* __restrict__ Qh,
                                                ushort_t* __restrict__ Kh,
                                                ushort_t* __restrict__ Vt,
                                                float Cs) {
    constexpr int K = 512;
    __shared__ ushort_t As[128][72];
    __shared__ __attribute__((aligned(16))) char Bimg[16384];   // 2 x 8KB

    const int which = blockIdx.y;
    const float*    Ap   = (which == 0) ? qi : (which == 1) ? ki : vi;
    const ushort_t* Wb   = Wball + (size_t)which * 262144;
    const float*    bias = (which == 0) ? bq : (which == 1) ? bk : bv;
    ushort_t*       outp = (which == 0) ? Qh : (which == 1) ? Kh : Vt;

    int bid = blockIdx.x;
    bid = (bid & 7) * 64 + (bid >> 3);    // XCD-affine bijective remap (nwg=512)
    const int bm = bid >> 3;              // 0..63
    const int bn = bid & 7;
    const int m0 = bm * 128, n0 = bn * 64;
    const int t    = threadIdx.x;
    const int lane = t & 63;
    const int wv   = t >> 6;
    const int wm   = wv >> 1, wn = wv & 1;
    const int lrow = t >> 1;              // 0..127
    const int lcol = (t & 1) * 32;        // 0 or 32

    const int l15 = lane & 15;
    const int l16 = lane >> 4;

    f32x4 acc[4][2] = {};

    const float*    apf = Ap + (size_t)(m0 + lrow) * K + lcol;
    const ushort_t* wgp = Wb + (size_t)bn * 8 * 4096 + wv * 1024 + lane * 8;

    auto issueB = [&](int kt, int cur) {
        const ushort_t* p = wgp + (size_t)kt * 4096;
        gload16(p,       Bimg + cur * 8192 + wv * 2048);
        gload16(p + 512, Bimg + cur * 8192 + wv * 2048 + 1024);
    };

    f32x4 af[8];
#pragma unroll
    for (int i = 0; i < 8; ++i) af[i] = *(const f32x4*)(apf + i * 4);
    issueB(0, 0);

#pragma unroll 1
    for (int kt = 0; kt < K / 64; ++kt) {
        const int cur = kt & 1;
        __syncthreads();      // compute(kt-1) done; drains B(kt) gload
        {
            unsigned tw[16];
#pragma unroll
            for (int i = 0; i < 8; ++i) {
                tw[2 * i]     = cvtpk(af[i][0], af[i][1]);
                tw[2 * i + 1] = cvtpk(af[i][2], af[i][3]);
            }
#pragma unroll
            for (int c = 0; c < 4; ++c)
                *(u32x4*)&As[lrow][lcol + c * 8] = *(u32x4*)(tw + c * 4);
        }
        __syncthreads();      // A visible

        if (kt < K / 64 - 1) {
            issueB(kt + 1, cur ^ 1);      // lands during compute(kt)
            const float* s = apf + (kt + 1) * 64;
#pragma unroll
            for (int i = 0; i < 8; ++i) af[i] = *(const f32x4*)(s + i * 4);
        }

        const char* lbB = Bimg + cur * 8192 + lane * 16;
#pragma unroll
        for (int kk = 0; kk < 2; ++kk) {
            bf16x8 a[4], b[2];
#pragma unroll
            for (int i = 0; i < 4; ++i)
                a[i] = *(const bf16x8*)&As[wm * 64 + i * 16 + l15][kk * 32 + l16 * 8];
#pragma unroll
            for (int j = 0; j < 2; ++j)
                b[j] = *(const bf16x8*)(lbB + (wn * 4 + j * 2 + kk) * 1024);
#pragma unroll
            for (int i = 0; i < 4; ++i)
#pragma unroll
                for (int j = 0; j < 2; ++j)
                    acc[i][j] = MFMA16(a[i], b[j], acc[i][j]);
        }
    }

#pragma unroll
    for (int i = 0; i < 4; ++i)
#pragma unroll
        for (int j = 0; j < 2; ++j) {
            const int n  = n0 + wn * 32 + j * 16 + l15;
            const float bv_ = bias[n];
            const int h = n >> 6, d = n & 63;
            if (which == 2) {
                // V^T chunk-ordered (attn PV layout, r15-verified)
                const int mbase = m0 + wm * 64 + i * 16 + l16 * 4;
                const int b = mbase >> 12, key = mbase & 4095;
                const int keyr = key & 63;
                const int ks = keyr >> 4, hc = (keyr >> 3) & 1, e0 = keyr & 7;
                const int db = d >> 5, dr = d & 31;
                ushort_t tmp[4];
#pragma unroll
                for (int v = 0; v < 4; ++v) tmp[v] = f2bf(acc[i][j][v] + bv_);
                *(us4*)(outp + (size_t)(b * 8 + h) * 262144 +
                        (size_t)(key >> 6) * 4096 +
                        db * 2048 + ks * 512 + (hc * 32 + dr) * 8 + e0) = *(us4*)tmp;
            } else if (which == 1) {
                // K chunk-ordered (attn QK layout, r15-verified)
                const int jd = d >> 4, hc = (d >> 3) & 1, e = d & 7;
#pragma unroll
                for (int v = 0; v < 4; ++v) {
                    const int m = m0 + wm * 64 + i * 16 + l16 * 4 + v;
                    const int b = m >> 12, s = m & 4095;
                    const int r = s & 63, kb2 = r >> 5, kr = r & 31;
                    outp[(size_t)(b * 8 + h) * 262144 + (size_t)(s >> 6) * 4096 +
                         kb2 * 2048 + jd * 512 + (hc * 32 + kr) * 8 + e] =
                        f2bf(acc[i][j][v] + bv_);
                }
            } else {
#pragma unroll
                for (int v = 0; v < 4; ++v) {
                    const int m = m0 + wm * 64 + i * 16 + l16 * 4 + v;
                    const int b = m >> 12, s = m & 4095;
                    outp[(((size_t)(b * 8 + h)) * 4096 + s) * 64 + d] =
                        f2bf((acc[i][j][v] + bv_) * Cs);
                }
            }
        }
}

// ---------------------------------------------------------------------------
// Output NT-GEMM: 128x64 tile, BK=64, grid 512. A = chunk-ordered AO (two
// 64-tiles per k-iter), B = chunk-ordered Wo, both via global_load_lds dbuf.
// ---------------------------------------------------------------------------
__global__ __launch_bounds__(256) void gemm_out(const ushort_t* __restrict__ AOc,
                                                const ushort_t* __restrict__ Wo,
                                                const float* __restrict__ bias,
                                                float* __restrict__ outp) {
    __shared__ __attribute__((aligned(16))) char Img[49152];
    // A buffers (16KB each) @ 0 / 16384 ; B buffers (8KB each) @ 32768 / 40960

    int bid = blockIdx.x;
    bid = (bid & 7) * 64 + (bid >> 3);    // XCD-affine bijective remap (nwg=512)
    const int bm = bid >> 3;              // 0..63
    const int bn = bid & 7;
    const int m0 = bm * 128, n0 = bn * 64;
    const int t    = threadIdx.x;
    const int lane = t & 63;
    const int wv   = t >> 6;
    const int wm   = wv >> 1, wn = wv & 1;
    const int l15  = lane & 15;
    const int l16  = lane >> 4;

    f32x4 acc[4][2] = {};

    const ushort_t* agp = AOc + ((size_t)bm * 2 * 8) * 4096 + wv * 1024 + lane * 8;
    const ushort_t* bgp = Wo  + (size_t)bn * 8 * 4096 + wv * 1024 + lane * 8;

    auto issue = [&](int kt, int cur) {
        const ushort_t* pa0 = agp + (size_t)kt * 4096;            // A tile 2*bm
        const ushort_t* pa1 = pa0 + (size_t)8 * 4096;             // A tile 2*bm+1
        gload16(pa0,       Img + cur * 16384 + wv * 2048);
        gload16(pa0 + 512, Img + cur * 16384 + wv * 2048 + 1024);
        gload16(pa1,       Img + cur * 16384 + 8192 + wv * 2048);
        gload16(pa1 + 512, Img + cur * 16384 + 8192 + wv * 2048 + 1024);
        const ushort_t* pb = bgp + (size_t)kt * 4096;
        gload16(pb,       Img + 32768 + cur * 8192 + wv * 2048);
        gload16(pb + 512, Img + 32768 + cur * 8192 + wv * 2048 + 1024);
    };

    issue(0, 0);
    __syncthreads();     // drains A(0)/B(0)

#pragma unroll 1
    for (int kt = 0; kt < 8; ++kt) {
        const int cur = kt & 1;
        if (kt < 7) issue(kt + 1, cur ^ 1);    // lands during compute(kt)

        const char* lbA = Img + cur * 16384 + wm * 8192 + lane * 16;
        const char* lbB = Img + 32768 + cur * 8192 + lane * 16;
#pragma unroll
        for (int kk = 0; kk < 2; ++kk) {
            bf16x8 a[4], b[2];
#pragma unroll
            for (int i = 0; i < 4; ++i)
                a[i] = *(const bf16x8*)(lbA + ((i >> 1) * 4 + (i & 1) * 2 + kk) * 1024);
#pragma unroll
            for (int j = 0; j < 2; ++j)
                b[j] = *(const bf16x8*)(lbB + (wn * 4 + j * 2 + kk) * 1024);
#pragma unroll
            for (int i = 0; i < 4; ++i)
#pragma unroll
                for (int j = 0; j < 2; ++j)
                    acc[i][j] = MFMA16(a[i], b[j], acc[i][j]);
        }
        __syncthreads();   // all waves done reading buf cur; drains (kt+1) gloads
    }

#pragma unroll
    for (int i = 0; i < 4; ++i)
#pragma unroll
        for (int j = 0; j < 2; ++j) {
            const int n  = n0 + wn * 32 + j * 16 + l15;
            const float bv_ = bias[n];
#pragma unroll
            for (int v = 0; v < 4; ++v) {
                const int m = m0 + wm * 64 + i * 16 + l16 * 4 + v;
                outp[(size_t)m * 512 + n] = acc[i][j][v] + bv_;
            }
        }
}

// ---------------------------------------------------------------------------
// Flash attention (r15 EXACT revert — best measured: 90.6 us): swapped-QK^T
// 32x32, zero-shift softmax, SW-pipelined (QK(t+1) before softmax(t)),
// K 2-slot + V 3-slot LDS (40KB), chunk-ordered K/V via global_load_lds,
// conflict-free imm-offset reads, XCD-affine bh pinning, chunk-ordered AO out.
// ---------------------------------------------------------------------------
__global__ __launch_bounds__(256) void attn_fwd(const ushort_t* __restrict__ Qh,
                                                const ushort_t* __restrict__ Kg,
                                                const ushort_t* __restrict__ Vg,
                                                ushort_t* __restrict__ Out) {
    constexpr int S  = 4096;
    __shared__ __attribute__((aligned(16))) char LDS[40960];
    // K slots @ 0 / 8192 ; V slots @ 16384 / 24576 / 32768

    const int id   = blockIdx.x;          // 0..511
    const int xcd  = id & 7;
    const int slot = id >> 3;             // 0..63
    const int qt   = slot & 31;
    const int bh   = xcd * 2 + (slot >> 5);
    const int b    = bh >> 3, h = bh & 7;

    const int t    = threadIdx.x;
    const int lane = t & 63;
    const int wv   = t >> 6;
    const int l31  = lane & 31;
    const int hl   = lane >> 5;

    const int qw = qt * 128 + wv * 32;

    // Q fragments (B operand): col=q=l31, k = ds*16 + 8*hl + j
    bf16x8 qf[4];
    {
        const ushort_t* qp = Qh + ((size_t)bh * S + qw + l31) * 64 + hl * 8;
#pragma unroll
        for (int ds = 0; ds < 4; ++ds) qf[ds] = *(const bf16x8*)(qp + ds * 16);
    }

    const f32x16 fzero = {};
    f32x16 accO[2] = {};
    float ll = 0.f;

    const char* lbase = LDS + lane * 16;
    const int wvb = wv * 1024;
    const ushort_t* kg = Kg + (size_t)bh * 262144 + wv * 512 + lane * 8;
    const ushort_t* vg = Vg + (size_t)bh * 262144 + wv * 512 + lane * 8;

    auto issueK = [&](int kt, int kslotB) {
        const ushort_t* p = kg + (size_t)kt * 4096;
        gload16(p,        LDS + kslotB + wvb);
        gload16(p + 2048, LDS + kslotB + 4096 + wvb);
    };
    auto issueV = [&](int kt, int vslotB) {
        const ushort_t* p = vg + (size_t)kt * 4096;
        gload16(p,        LDS + vslotB + wvb);
        gload16(p + 2048, LDS + vslotB + 4096 + wvb);
    };

    auto QK = [&](auto kc, f32x16& s0, f32x16& s1) {
        constexpr int KB = decltype(kc)::value;
        __builtin_amdgcn_s_setprio(1);
        {
            bf16x8 kf = *(const bf16x8*)(lbase + KB);
            s0 = MFMA32(kf, qf[0], fzero);
        }
#pragma unroll
        for (int ds = 1; ds < 4; ++ds) {
            bf16x8 kf = *(const bf16x8*)(lbase + KB + ds * 1024);
            s0 = MFMA32(kf, qf[ds], s0);
        }
        {
            bf16x8 kf = *(const bf16x8*)(lbase + KB + 4096);
            s1 = MFMA32(kf, qf[0], fzero);
        }
#pragma unroll
        for (int ds = 1; ds < 4; ++ds) {
            bf16x8 kf = *(const bf16x8*)(lbase + KB + 4096 + ds * 1024);
            s1 = MFMA32(kf, qf[ds], s1);
        }
        __builtin_amdgcn_s_setprio(0);
    };

    auto SOFTPV = [&](f32x16& sc0, f32x16& sc1, int vbase) {
#pragma unroll
        for (int i = 0; i < 16; ++i) {
            sc0[i] = __builtin_amdgcn_exp2f(sc0[i]);
            sc1[i] = __builtin_amdgcn_exp2f(sc1[i]);
        }
        {
#define PAIR(v, i) __builtin_shufflevector((v), (v), 2 * (i), 2 * (i) + 1)
            f32x2 pa  = (PAIR(sc0, 0) + PAIR(sc0, 1)) + (PAIR(sc0, 2) + PAIR(sc0, 3));
            f32x2 pbt = (PAIR(sc0, 4) + PAIR(sc0, 5)) + (PAIR(sc0, 6) + PAIR(sc0, 7));
            f32x2 pc  = (PAIR(sc1, 0) + PAIR(sc1, 1)) + (PAIR(sc1, 2) + PAIR(sc1, 3));
            f32x2 pd  = (PAIR(sc1, 4) + PAIR(sc1, 5)) + (PAIR(sc1, 6) + PAIR(sc1, 7));
            f32x2 s2  = (pa + pbt) + (pc + pd);
            ll += s2.x + s2.y;
#undef PAIR
        }
        bf16x8 pb[4];
#pragma unroll
        for (int ks = 0; ks < 4; ++ks) {
            const int R0 = (ks & 1) * 8;
            float e0, e1, e2, e3, e4, e5, e6, e7;
            if (ks < 2) {
                e0 = sc0[R0+0]; e1 = sc0[R0+1]; e2 = sc0[R0+2]; e3 = sc0[R0+3];
                e4 = sc0[R0+4]; e5 = sc0[R0+5]; e6 = sc0[R0+6]; e7 = sc0[R0+7];
            } else {
                e0 = sc1[R0+0]; e1 = sc1[R0+1]; e2 = sc1[R0+2]; e3 = sc1[R0+3];
                e4 = sc1[R0+4]; e5 = sc1[R0+5]; e6 = sc1[R0+6]; e7 = sc1[R0+7];
            }
            unsigned w0 = cvtpk(e0, e1);
            unsigned w1 = cvtpk(e2, e3);
            unsigned w2 = cvtpk(e4, e5);
            unsigned w3 = cvtpk(e6, e7);
            uint2v s02 = __builtin_amdgcn_permlane32_swap(w0, w2, false, false);
            uint2v s13 = __builtin_amdgcn_permlane32_swap(w1, w3, false, false);
            u32x4 w = {s02.x, s13.x, s02.y, s13.y};
            pb[ks] = __builtin_bit_cast(bf16x8, w);
        }
        const char* vb = LDS + vbase + lane * 16;
        __builtin_amdgcn_s_setprio(1);
#pragma unroll
        for (int ks = 0; ks < 4; ++ks) {
            {
                bf16x8 vf = *(const bf16x8*)(vb + ks * 1024);
                accO[0] = MFMA32(vf, pb[ks], accO[0]);
            }
            {
                bf16x8 vf = *(const bf16x8*)(vb + 4096 + ks * 1024);
                accO[1] = MFMA32(vf, pb[ks], accO[1]);
            }
        }
        __builtin_amdgcn_s_setprio(0);
    };

    int v0b = 16384, v1b = 24576, v2b = 32768;

    issueK(0, 0);
    issueK(1, 8192);
    issueV(0, v0b);
    issueV(1, v1b);
    __syncthreads();

    f32x16 sA0, sA1, sB0, sB1;
    QK(ic<0>{}, sA0, sA1);

#pragma unroll 1
    for (int tp = 0; tp < 31; ++tp) {
        const int te = 2 * tp;
        __syncthreads();
        issueK(te + 2, 0);
        issueV(te + 2, v2b);
        QK(ic<8192>{}, sB0, sB1);
        SOFTPV(sA0, sA1, v0b);
        { int tmp = v0b; v0b = v1b; v1b = v2b; v2b = tmp; }
        __syncthreads();
        issueK(te + 3, 8192);
        issueV(te + 3, v2b);
        QK(ic<0>{}, sA0, sA1);
        SOFTPV(sB0, sB1, v0b);
        { int tmp = v0b; v0b = v1b; v1b = v2b; v2b = tmp; }
    }

    __syncthreads();
    QK(ic<8192>{}, sB0, sB1);
    SOFTPV(sA0, sA1, v0b);
    { int tmp = v0b; v0b = v1b; v1b = v2b; v2b = tmp; }
    SOFTPV(sB0, sB1, v0b);

    // epilogue: write AO chunk-ordered for gemm_out (r15-proven formulas)
    const float lt  = ll + __shfl_xor(ll, 32);
    const float inv = 1.0f / lt;
    const int mrow = qw + l31;
    const int bmA  = b * 64 + (mrow >> 6);
    const int rr   = mrow & 63;
    const int wmr  = rr >> 5, i2r = (rr >> 4) & 1, l15r = rr & 15;
    ushort_t* obase = Out + ((size_t)bmA * 8 + h) * 4096 +
                      (size_t)(wmr * 4 + i2r * 2) * 512 + l15r * 8 + hl * 4;
#pragma unroll
    for (int db = 0; db < 2; ++db)
#pragma unroll
        for (int q4 = 0; q4 < 4; ++q4) {
            unsigned w0 = cvtpk(accO[db][q4 * 4 + 0] * inv, accO[db][q4 * 4 + 1] * inv);
            unsigned w1 = cvtpk(accO[db][q4 * 4 + 2] * inv, accO[db][q4 * 4 + 3] * inv);
            unsigned tmp[2] = {w0, w1};
            *(us4*)(obase + db * 512 + q4 * 128) = *(const us4*)tmp;
        }
}

// ---------------------------------------------------------------------------
extern "C" void kernel_launch(void* const* d_in, const int* in_sizes, int n_in,
                              void* d_out, int out_size, void* d_ws, size_t ws_size,
                              hipStream_t stream) {
    const float* q  = (const float*)d_in[0];
    const float* k  = (const float*)d_in[1];
    const float* v  = (const float*)d_in[2];
    const float* Wq = (const float*)d_in[3];
    const float* bq = (const float*)d_in[4];
    const float* bk = (const float*)d_in[6];
    const float* bv = (const float*)d_in[8];
    const float* bo = (const float*)d_in[10];

    char* w = (char*)d_ws;
    const size_t SZ = (size_t)2 * 8 * 4096 * 64 * 2;   // 8 MB per buffer

    ushort_t* Qh  = (ushort_t*)(w);
    ushort_t* Kh  = (ushort_t*)(w + SZ);
    ushort_t* Vtr = (ushort_t*)(w + 2 * SZ);
    ushort_t* AO  = (ushort_t*)(w + 3 * SZ);
    ushort_t* Wb  = (ushort_t*)(w + 4 * SZ);           // 2 MB bf16 weights

    cvt_w<<<dim3(128, 4), 256, 0, stream>>>(Wq, (const float*)d_in[5],
                                            (const float*)d_in[7], (const float*)d_in[9], Wb);

    const float Cs = 0.125f * 1.44269504f;  // softmax scale * log2(e), folded into Q
    gemm_qkv<<<dim3(512, 3), 256, 0, stream>>>(q, k, v, Wb, bq, bk, bv, Qh, Kh, Vtr, Cs);

    attn_fwd<<<512, 256, 0, stream>>>(Qh, Kh, Vtr, AO);

    gemm_out<<<512, 256, 0, stream>>>(AO, Wb + 3 * 262144, bo, (float*)d_out);
}

// Round 18
// 134.295 us; speedup vs baseline: 1.1464x; 1.1464x over previous
//
#include <hip/hip_runtime.h>

typedef short bf16x8 __attribute__((ext_vector_type(8)));
typedef float f32x2 __attribute__((ext_vector_type(2)));
typedef float f32x4 __attribute__((ext_vector_type(4)));
typedef float f32x16 __attribute__((ext_vector_type(16)));
typedef unsigned short ushort_t;
typedef unsigned short us8 __attribute__((ext_vector_type(8)));
typedef unsigned short us4 __attribute__((ext_vector_type(4)));
typedef unsigned int u32x4 __attribute__((ext_vector_type(4)));
typedef unsigned int uint2v __attribute__((ext_vector_type(2)));

#define MFMA16(a, b, c) __builtin_amdgcn_mfma_f32_16x16x32_bf16((a), (b), (c), 0, 0, 0)
#define MFMA32(a, b, c) __builtin_amdgcn_mfma_f32_32x32x16_bf16((a), (b), (c), 0, 0, 0)

template <int N> struct ic { static constexpr int value = N; };

static __device__ __forceinline__ ushort_t f2bf(float f) {
    unsigned int u = __builtin_bit_cast(unsigned int, f);
    u += 0x7FFFu + ((u >> 16) & 1u);   // RNE
    return (ushort_t)(u >> 16);
}

static __device__ __forceinline__ unsigned cvtpk(float lo, float hi) {
    unsigned r;
    asm("v_cvt_pk_bf16_f32 %0, %1, %2" : "=v"(r) : "v"(lo), "v"(hi));
    return r;
}

// global -> LDS direct async copy, 16B per lane (LDS dest = wave-uniform base + lane*16)
static __device__ __forceinline__ void gload16(const void* g, void* l) {
    __builtin_amdgcn_global_load_lds(
        (const __attribute__((address_space(1))) unsigned int*)g,
        (__attribute__((address_space(3))) unsigned int*)l,
        16, 0, 0);
}

// ---------------------------------------------------------------------------
// Convert 4 fp32 512x512 weight matrices to bf16 in CHUNK ORDER:
// per 64x64 tile (bn,kt), fragment (wn,j,kk) = contiguous 1KB block, lane
// (l16*16+l15) holds elem (n = bn*64+wn*32+j*16+l15, k = kt*64+kk*32+l16*8+e).
// ---------------------------------------------------------------------------
__global__ __launch_bounds__(256) void cvt_w(const float* __restrict__ W0,
                                             const float* __restrict__ W1,
                                             const float* __restrict__ W2,
                                             const float* __restrict__ W3,
                                             ushort_t* __restrict__ dst) {
    const float* src = (blockIdx.y == 0) ? W0 : (blockIdx.y == 1) ? W1
                     : (blockIdx.y == 2) ? W2 : W3;
    const int i = (blockIdx.x * 256 + threadIdx.x) * 8;
    const int n = i >> 9, k = i & 511;
    float4 f0 = *(const float4*)(src + i);
    float4 f1 = *(const float4*)(src + i + 4);
    unsigned tw[4] = {cvtpk(f0.x, f0.y), cvtpk(f0.z, f0.w),
                      cvtpk(f1.x, f1.y), cvtpk(f1.z, f1.w)};
    const int bn = n >> 6, r = n & 63;
    const int wn = r >> 5, j = (r >> 4) & 1, l15 = r & 15;
    const int kt = k >> 6, c = k & 63;
    const int kk = c >> 5, l16 = (c >> 3) & 3;
    const size_t off = (size_t)blockIdx.y * 262144 +
        (size_t)((bn * 8 + kt) * 4096 + (wn * 4 + j * 2 + kk) * 512 +
                 (l16 * 16 + l15) * 8);
    *(u32x4*)(dst + off) = *(u32x4*)tw;
}

// ---------------------------------------------------------------------------
// Fused Q/K/V projection NT-GEMM, 64x64 tile, BK=64, grid (1024,3).
// A (fp32): reg-load + cvt_pk -> padded LDS (proven path).
// B (bf16 chunk-ordered weights): global_load_lds, double-buffered image;
// fragment reads = lane*16 + immediate (conflict-free, zero staging VALU).
// Epilogues identical to r9-verified:
// y=0: Q row-major [B*H][S][64] * Cs; y=1: K chunk tiles; y=2: V^T chunk tiles.
// ---------------------------------------------------------------------------
__global__ __launch_bounds__(256) void gemm_qkv(const float* __restrict__ qi,
                                                const float* __restrict__ ki,
                                                const float* __restrict__ vi,
                                                const ushort_t* __restrict__ Wball,
                                                const float* __restrict__ bq,
                                                const float* __restrict__ bk,
                                                const float* __restrict__ bv,
                                                ushort_t* __restrict__ Qh,
                                                ushort_t* __restrict__ Kh,
                                                ushort_t* __restrict__ Vt,
                                                float Cs) {
    constexpr int K = 512;
    __shared__ ushort_t As[64][72];
    __shared__ __attribute__((aligned(16))) char Bimg[16384];   // 2 x 8KB

    const int which = blockIdx.y;
    const float*    Ap   = (which == 0) ? qi : (which == 1) ? ki : vi;
    const ushort_t* Wb   = Wball + (size_t)which * 262144;
    const float*    bias = (which == 0) ? bq : (which == 1) ? bk : bv;
    ushort_t*       outp = (which == 0) ? Qh : (which == 1) ? Kh : Vt;

    int bid = blockIdx.x;
    bid = (bid & 7) * 128 + (bid >> 3);   // XCD-affine bijective remap (nwg=1024)
    const int bm = bid >> 3;
    const int bn = bid & 7;
    const int m0 = bm * 64, n0 = bn * 64;
    const int t    = threadIdx.x;
    const int lane = t & 63;
    const int wv   = t >> 6;
    const int wm   = wv >> 1, wn = wv & 1;
    const int lrow = t >> 2;
    const int lcol = (t & 3) * 16;

    const int l15 = lane & 15;
    const int l16 = lane >> 4;

    f32x4 acc[2][2] = {};

    const float*    apf = Ap + (size_t)(m0 + lrow) * K + lcol;
    const ushort_t* wgp = Wb + (size_t)bn * 8 * 4096 + wv * 1024 + lane * 8;

    auto issueB = [&](int kt, int cur) {
        const ushort_t* p = wgp + (size_t)kt * 4096;
        gload16(p,       Bimg + cur * 8192 + wv * 2048);
        gload16(p + 512, Bimg + cur * 8192 + wv * 2048 + 1024);
    };

    f32x4 af[4];
    af[0] = *(const f32x4*)apf;       af[1] = *(const f32x4*)(apf + 4);
    af[2] = *(const f32x4*)(apf + 8); af[3] = *(const f32x4*)(apf + 12);
    issueB(0, 0);

#pragma unroll 1
    for (int kt = 0; kt < K / 64; ++kt) {
        const int cur = kt & 1;
        __syncthreads();      // compute(kt-1) done; drains B(kt) gload
        {
            unsigned tw[8];
#pragma unroll
            for (int i = 0; i < 4; ++i) {
                tw[2 * i]     = cvtpk(af[i][0], af[i][1]);
                tw[2 * i + 1] = cvtpk(af[i][2], af[i][3]);
            }
            *(u32x4*)&As[lrow][lcol]     = *(u32x4*)tw;
            *(u32x4*)&As[lrow][lcol + 8] = *(u32x4*)(tw + 4);
        }
        __syncthreads();      // A visible

        if (kt < K / 64 - 1) {
            issueB(kt + 1, cur ^ 1);            // lands during compute(kt)
            const float* s = apf + (kt + 1) * 64;
            af[0] = *(const f32x4*)s;       af[1] = *(const f32x4*)(s + 4);
            af[2] = *(const f32x4*)(s + 8); af[3] = *(const f32x4*)(s + 12);
        }

        const char* lbB = Bimg + cur * 8192 + wn * 4096 + lane * 16;
#pragma unroll
        for (int kk = 0; kk < 2; ++kk) {
            bf16x8 a0 = *(const bf16x8*)&As[wm * 32 + l15][kk * 32 + l16 * 8];
            bf16x8 a1 = *(const bf16x8*)&As[wm * 32 + 16 + l15][kk * 32 + l16 * 8];
            bf16x8 b0 = *(const bf16x8*)(lbB + kk * 1024);
            bf16x8 b1 = *(const bf16x8*)(lbB + 2048 + kk * 1024);
            acc[0][0] = MFMA16(a0, b0, acc[0][0]);
            acc[0][1] = MFMA16(a0, b1, acc[0][1]);
            acc[1][0] = MFMA16(a1, b0, acc[1][0]);
            acc[1][1] = MFMA16(a1, b1, acc[1][1]);
        }
    }

#pragma unroll
    for (int i = 0; i < 2; ++i)
#pragma unroll
        for (int j = 0; j < 2; ++j) {
            const int n  = n0 + wn * 32 + j * 16 + l15;
            const float bv_ = bias[n];
            const int h = n >> 6, d = n & 63;
            if (which == 2) {
                // V^T chunk-ordered (attn PV layout)
                const int mbase = m0 + wm * 32 + i * 16 + l16 * 4;
                const int b = mbase >> 12, key = mbase & 4095;
                const int keyr = key & 63;
                const int ks = keyr >> 4, hc = (keyr >> 3) & 1, e0 = keyr & 7;
                const int db = d >> 5, dr = d & 31;
                ushort_t tmp[4];
#pragma unroll
                for (int v = 0; v < 4; ++v) tmp[v] = f2bf(acc[i][j][v] + bv_);
                *(us4*)(outp + (size_t)(b * 8 + h) * 262144 +
                        (size_t)(key >> 6) * 4096 +
                        db * 2048 + ks * 512 + (hc * 32 + dr) * 8 + e0) = *(us4*)tmp;
            } else if (which == 1) {
                // K chunk-ordered (attn QK layout)
                const int jd = d >> 4, hc = (d >> 3) & 1, e = d & 7;
#pragma unroll
                for (int v = 0; v < 4; ++v) {
                    const int m = m0 + wm * 32 + i * 16 + l16 * 4 + v;
                    const int b = m >> 12, s = m & 4095;
                    const int r = s & 63, kb2 = r >> 5, kr = r & 31;
                    outp[(size_t)(b * 8 + h) * 262144 + (size_t)(s >> 6) * 4096 +
                         kb2 * 2048 + jd * 512 + (hc * 32 + kr) * 8 + e] =
                        f2bf(acc[i][j][v] + bv_);
                }
            } else {
#pragma unroll
                for (int v = 0; v < 4; ++v) {
                    const int m = m0 + wm * 32 + i * 16 + l16 * 4 + v;
                    const int b = m >> 12, s = m & 4095;
                    outp[(((size_t)(b * 8 + h)) * 4096 + s) * 64 + d] =
                        f2bf((acc[i][j][v] + bv_) * Cs);
                }
            }
        }
}

// ---------------------------------------------------------------------------
// Output NT-GEMM: A = chunk-ordered AO (written by attn), B = chunk-ordered
// Wo. BOTH staged via global_load_lds into double-buffered images -> zero
// staging VALU, ONE barrier per k-iter. 64x64 tile, BK=64, grid 1024.
// ---------------------------------------------------------------------------
__global__ __launch_bounds__(256) void gemm_out(const ushort_t* __restrict__ AOc,
                                                const ushort_t* __restrict__ Wo,
                                                const float* __restrict__ bias,
                                                float* __restrict__ outp) {
    __shared__ __attribute__((aligned(16))) char Img[32768];
    // A buffers @ 0 / 8192 ; B buffers @ 16384 / 24576

    int bid = blockIdx.x;
    bid = (bid & 7) * 128 + (bid >> 3);
    const int bm = bid >> 3;     // 0..127
    const int bn = bid & 7;      // 0..7
    const int m0 = bm * 64, n0 = bn * 64;
    const int t    = threadIdx.x;
    const int lane = t & 63;
    const int wv   = t >> 6;
    const int wm   = wv >> 1, wn = wv & 1;
    const int l15  = lane & 15;
    const int l16  = lane >> 4;

    f32x4 acc[2][2] = {};

    const ushort_t* agp = AOc + (size_t)bm * 8 * 4096 + wv * 1024 + lane * 8;
    const ushort_t* bgp = Wo  + (size_t)bn * 8 * 4096 + wv * 1024 + lane * 8;

    auto issue = [&](int kt, int cur) {
        const ushort_t* pa = agp + (size_t)kt * 4096;
        gload16(pa,       Img + cur * 8192 + wv * 2048);
        gload16(pa + 512, Img + cur * 8192 + wv * 2048 + 1024);
        const ushort_t* pb = bgp + (size_t)kt * 4096;
        gload16(pb,       Img + 16384 + cur * 8192 + wv * 2048);
        gload16(pb + 512, Img + 16384 + cur * 8192 + wv * 2048 + 1024);
    };

    issue(0, 0);
    __syncthreads();     // drains A(0)/B(0)

#pragma unroll 1
    for (int kt = 0; kt < 8; ++kt) {
        const int cur = kt & 1;
        if (kt < 7) issue(kt + 1, cur ^ 1);    // lands during compute(kt)

        const char* lbA = Img + cur * 8192 + wm * 4096 + lane * 16;
        const char* lbB = Img + 16384 + cur * 8192 + wn * 4096 + lane * 16;
#pragma unroll
        for (int kk = 0; kk < 2; ++kk) {
            bf16x8 a0 = *(const bf16x8*)(lbA + kk * 1024);
            bf16x8 a1 = *(const bf16x8*)(lbA + 2048 + kk * 1024);
            bf16x8 b0 = *(const bf16x8*)(lbB + kk * 1024);
            bf16x8 b1 = *(const bf16x8*)(lbB + 2048 + kk * 1024);
            acc[0][0] = MFMA16(a0, b0, acc[0][0]);
            acc[0][1] = MFMA16(a0, b1, acc[0][1]);
            acc[1][0] = MFMA16(a1, b0, acc[1][0]);
            acc[1][1] = MFMA16(a1, b1, acc[1][1]);
        }
        __syncthreads();   // all waves done reading buf cur; drains (kt+1) gloads
    }

#pragma unroll
    for (int i = 0; i < 2; ++i)
#pragma unroll
        for (int j = 0; j < 2; ++j) {
            const int n  = n0 + wn * 32 + j * 16 + l15;
            const float bv_ = bias[n];
#pragma unroll
            for (int v = 0; v < 4; ++v) {
                const int m = m0 + wm * 32 + i * 16 + l16 * 4 + v;
                outp[(size_t)m * 512 + n] = acc[i][j][v] + bv_;
            }
        }
}

// ---------------------------------------------------------------------------
// Flash attention (best measured: 90.6 us): swapped-QK^T 32x32, zero-shift
// softmax, SW-pipelined (QK(t+1) before softmax(t)), K 2-slot + V 3-slot LDS
// (40KB), chunk-ordered K/V via global_load_lds, conflict-free imm-offset
// reads, XCD-affine bh pinning, chunk-ordered AO epilogue.
// ---------------------------------------------------------------------------
__global__ __launch_bounds__(256) void attn_fwd(const ushort_t* __restrict__ Qh,
                                                const ushort_t* __restrict__ Kg,
                                                const ushort_t* __restrict__ Vg,
                                                ushort_t* __restrict__ Out) {
    constexpr int S  = 4096;
    __shared__ __attribute__((aligned(16))) char LDS[40960];
    // K slots @ 0 / 8192 ; V slots @ 16384 / 24576 / 32768

    const int id   = blockIdx.x;          // 0..511
    const int xcd  = id & 7;
    const int slot = id >> 3;             // 0..63
    const int qt   = slot & 31;
    const int bh   = xcd * 2 + (slot >> 5);
    const int b    = bh >> 3, h = bh & 7;

    const int t    = threadIdx.x;
    const int lane = t & 63;
    const int wv   = t >> 6;
    const int l31  = lane & 31;
    const int hl   = lane >> 5;

    const int qw = qt * 128 + wv * 32;

    // Q fragments (B operand): col=q=l31, k = ds*16 + 8*hl + j
    bf16x8 qf[4];
    {
        const ushort_t* qp = Qh + ((size_t)bh * S + qw + l31) * 64 + hl * 8;
#pragma unroll
        for (int ds = 0; ds < 4; ++ds) qf[ds] = *(const bf16x8*)(qp + ds * 16);
    }

    const f32x16 fzero = {};
    f32x16 accO[2] = {};
    float ll = 0.f;

    const char* lbase = LDS + lane * 16;
    const int wvb = wv * 1024;
    const ushort_t* kg = Kg + (size_t)bh * 262144 + wv * 512 + lane * 8;
    const ushort_t* vg = Vg + (size_t)bh * 262144 + wv * 512 + lane * 8;

    auto issueK = [&](int kt, int kslotB) {
        const ushort_t* p = kg + (size_t)kt * 4096;
        gload16(p,        LDS + kslotB + wvb);
        gload16(p + 2048, LDS + kslotB + 4096 + wvb);
    };
    auto issueV = [&](int kt, int vslotB) {
        const ushort_t* p = vg + (size_t)kt * 4096;
        gload16(p,        LDS + vslotB + wvb);
        gload16(p + 2048, LDS + vslotB + 4096 + wvb);
    };

    auto QK = [&](auto kc, f32x16& s0, f32x16& s1) {
        constexpr int KB = decltype(kc)::value;
        __builtin_amdgcn_s_setprio(1);
        {
            bf16x8 kf = *(const bf16x8*)(lbase + KB);
            s0 = MFMA32(kf, qf[0], fzero);
        }
#pragma unroll
        for (int ds = 1; ds < 4; ++ds) {
            bf16x8 kf = *(const bf16x8*)(lbase + KB + ds * 1024);
            s0 = MFMA32(kf, qf[ds], s0);
        }
        {
            bf16x8 kf = *(const bf16x8*)(lbase + KB + 4096);
            s1 = MFMA32(kf, qf[0], fzero);
        }
#pragma unroll
        for (int ds = 1; ds < 4; ++ds) {
            bf16x8 kf = *(const bf16x8*)(lbase + KB + 4096 + ds * 1024);
            s1 = MFMA32(kf, qf[ds], s1);
        }
        __builtin_amdgcn_s_setprio(0);
    };

    auto SOFTPV = [&](f32x16& sc0, f32x16& sc1, int vbase) {
#pragma unroll
        for (int i = 0; i < 16; ++i) {
            sc0[i] = __builtin_amdgcn_exp2f(sc0[i]);
            sc1[i] = __builtin_amdgcn_exp2f(sc1[i]);
        }
        {
#define PAIR(v, i) __builtin_shufflevector((v), (v), 2 * (i), 2 * (i) + 1)
            f32x2 pa  = (PAIR(sc0, 0) + PAIR(sc0, 1)) + (PAIR(sc0, 2) + PAIR(sc0, 3));
            f32x2 pbt = (PAIR(sc0, 4) + PAIR(sc0, 5)) + (PAIR(sc0, 6) + PAIR(sc0, 7));
            f32x2 pc  = (PAIR(sc1, 0) + PAIR(sc1, 1)) + (PAIR(sc1, 2) + PAIR(sc1, 3));
            f32x2 pd  = (PAIR(sc1, 4) + PAIR(sc1, 5)) + (PAIR(sc1, 6) + PAIR(sc1, 7));
            f32x2 s2  = (pa + pbt) + (pc + pd);
            ll += s2.x + s2.y;
#undef PAIR
        }
        bf16x8 pb[4];
#pragma unroll
        for (int ks = 0; ks < 4; ++ks) {
            const int R0 = (ks & 1) * 8;
            float e0, e1, e2, e3, e4, e5, e6, e7;
            if (ks < 2) {
                e0 = sc0[R0+0]; e1 = sc0[R0+1]; e2 = sc0[R0+2]; e3 = sc0[R0+3];
                e4 = sc0[R0+4]; e5 = sc0[R0+5]; e6 = sc0[R0+6]; e7 = sc0[R0+7];
            } else {
                e0 = sc1[R0+0]; e1 = sc1[R0+1]; e2 = sc1[R0+2]; e3 = sc1[R0+3];
                e4 = sc1[R0+4]; e5 = sc1[R0+5]; e6 = sc1[R0+6]; e7 = sc1[R0+7];
            }
            unsigned w0 = cvtpk(e0, e1);
            unsigned w1 = cvtpk(e2, e3);
            unsigned w2 = cvtpk(e4, e5);
            unsigned w3 = cvtpk(e6, e7);
            uint2v s02 = __builtin_amdgcn_permlane32_swap(w0, w2, false, false);
            uint2v s13 = __builtin_amdgcn_permlane32_swap(w1, w3, false, false);
            u32x4 w = {s02.x, s13.x, s02.y, s13.y};
            pb[ks] = __builtin_bit_cast(bf16x8, w);
        }
        const char* vb = LDS + vbase + lane * 16;
        __builtin_amdgcn_s_setprio(1);
#pragma unroll
        for (int ks = 0; ks < 4; ++ks) {
            {
                bf16x8 vf = *(const bf16x8*)(vb + ks * 1024);
                accO[0] = MFMA32(vf, pb[ks], accO[0]);
            }
            {
                bf16x8 vf = *(const bf16x8*)(vb + 4096 + ks * 1024);
                accO[1] = MFMA32(vf, pb[ks], accO[1]);
            }
        }
        __builtin_amdgcn_s_setprio(0);
    };

    int v0b = 16384, v1b = 24576, v2b = 32768;

    issueK(0, 0);
    issueK(1, 8192);
    issueV(0, v0b);
    issueV(1, v1b);
    __syncthreads();

    f32x16 sA0, sA1, sB0, sB1;
    QK(ic<0>{}, sA0, sA1);

#pragma unroll 1
    for (int tp = 0; tp < 31; ++tp) {
        const int te = 2 * tp;
        __syncthreads();
        issueK(te + 2, 0);
        issueV(te + 2, v2b);
        QK(ic<8192>{}, sB0, sB1);
        SOFTPV(sA0, sA1, v0b);
        { int tmp = v0b; v0b = v1b; v1b = v2b; v2b = tmp; }
        __syncthreads();
        issueK(te + 3, 8192);
        issueV(te + 3, v2b);
        QK(ic<0>{}, sA0, sA1);
        SOFTPV(sB0, sB1, v0b);
        { int tmp = v0b; v0b = v1b; v1b = v2b; v2b = tmp; }
    }

    __syncthreads();
    QK(ic<8192>{}, sB0, sB1);
    SOFTPV(sA0, sA1, v0b);
    { int tmp = v0b; v0b = v1b; v1b = v2b; v2b = tmp; }
    SOFTPV(sB0, sB1, v0b);

    // epilogue: write AO chunk-ordered for gemm_out's gload_lds A staging.
    const float lt  = ll + __shfl_xor(ll, 32);
    const float inv = 1.0f / lt;
    const int mrow = qw + l31;
    const int bmA  = b * 64 + (mrow >> 6);
    const int rr   = mrow & 63;
    const int wmr  = rr >> 5, i2r = (rr >> 4) & 1, l15r = rr & 15;
    ushort_t* obase = Out + ((size_t)bmA * 8 + h) * 4096 +
                      (size_t)(wmr * 4 + i2r * 2) * 512 + l15r * 8 + hl * 4;
#pragma unroll
    for (int db = 0; db < 2; ++db)
#pragma unroll
        for (int q4 = 0; q4 < 4; ++q4) {
            unsigned w0 = cvtpk(accO[db][q4 * 4 + 0] * inv, accO[db][q4 * 4 + 1] * inv);
            unsigned w1 = cvtpk(accO[db][q4 * 4 + 2] * inv, accO[db][q4 * 4 + 3] * inv);
            unsigned tmp[2] = {w0, w1};
            *(us4*)(obase + db * 512 + q4 * 128) = *(const us4*)tmp;
        }
}

// ---------------------------------------------------------------------------
extern "C" void kernel_launch(void* const* d_in, const int* in_sizes, int n_in,
                              void* d_out, int out_size, void* d_ws, size_t ws_size,
                              hipStream_t stream) {
    const float* q  = (const float*)d_in[0];
    const float* k  = (const float*)d_in[1];
    const float* v  = (const float*)d_in[2];
    const float* Wq = (const float*)d_in[3];
    const float* bq = (const float*)d_in[4];
    const float* bk = (const float*)d_in[6];
    const float* bv = (const float*)d_in[8];
    const float* bo = (const float*)d_in[10];

    char* w = (char*)d_ws;
    const size_t SZ = (size_t)2 * 8 * 4096 * 64 * 2;   // 8 MB per buffer

    ushort_t* Qh  = (ushort_t*)(w);
    ushort_t* Kh  = (ushort_t*)(w + SZ);
    ushort_t* Vtr = (ushort_t*)(w + 2 * SZ);
    ushort_t* AO  = (ushort_t*)(w + 3 * SZ);
    ushort_t* Wb  = (ushort_t*)(w + 4 * SZ);           // 2 MB bf16 weights

    cvt_w<<<dim3(128, 4), 256, 0, stream>>>(Wq, (const float*)d_in[5],
                                            (const float*)d_in[7], (const float*)d_in[9], Wb);

    const float Cs = 0.125f * 1.44269504f;  // softmax scale * log2(e), folded into Q
    gemm_qkv<<<dim3(1024, 3), 256, 0, stream>>>(q, k, v, Wb, bq, bk, bv, Qh, Kh, Vtr, Cs);

    attn_fwd<<<512, 256, 0, stream>>>(Qh, Kh, Vtr, AO);

    gemm_out<<<1024, 256, 0, stream>>>(AO, Wb + 3 * 262144, bo, (float*)d_out);
}